// Round 2
// baseline (1358.342 us; speedup 1.0000x reference)
//
#include <hip/hip_runtime.h>
#include <hip/hip_bf16.h>

// Problem constants
#define TOTAL_LENGTH 8192
#define GRAPH_DIM    32000
#define EMBED_DIM    128
#define S_COUNT      64
#define N_STEP       256
#define BATCH        32

#define C0 30.0f   // fixed logsumexp offset; max |logit| bounded ~85 << 88+C0

typedef __bf16 bf16_8 __attribute__((ext_vector_type(8)));
typedef float  f32x4  __attribute__((ext_vector_type(4)));

__device__ __forceinline__ float bfu2f(unsigned short u) {
    union { unsigned int i; float f; } x; x.i = ((unsigned int)u) << 16; return x.f;
}
__device__ __forceinline__ float blo(unsigned int u) {
    union { unsigned int i; float f; } x; x.i = u << 16; return x.f;
}
__device__ __forceinline__ float bhi(unsigned int u) {
    union { unsigned int i; float f; } x; x.i = u & 0xffff0000u; return x.f;
}
__device__ __forceinline__ unsigned short f2b(float f) {   // RNE fp32->bf16
    union { float f; unsigned int i; } u; u.f = f;
    unsigned int r = u.i + 0x7fffu + ((u.i >> 16) & 1u);
    return (unsigned short)(r >> 16);
}

// ---------------------------------------------------------------------------
// Phase A: per-batch xtran + att0 + 256-step scan -> zs (bf16, [8192][128])
// Grid: 32 blocks (one per batch), 256 threads. Inputs fp32.
// Bug-compatible gather (reshape(4,B,S,E) of latent[zi]):
//   xq[b] = latent[zi[b/4]]      + (b%4)*8192
//   xk[b] = latent[zi[8 + b/4]]  + (b%4)*8192
//   xv[b] = latent[zi[16 + b/4]] + (b%4)*8192
//   xi[b] = latent[zi[24 + b/4]] + (b%4)*8192
// ---------------------------------------------------------------------------
__global__ __launch_bounds__(256) void phaseA(
    const float* __restrict__ latent,
    const int* __restrict__ zi,
    __hip_bfloat16* __restrict__ zs)
{
    __shared__ float sQ[64 * 129];          // padded stride 129
    __shared__ float sK[64 * 129];
    __shared__ float sS[64 * 65];           // scores, stride 65
    __shared__ float sT[64 * 65];           // xtran, stride 65
    __shared__ __align__(16) float sAtt[2][64];

    const int b   = blockIdx.x;
    const int tid = threadIdx.x;
    const size_t off = (size_t)(b & 3) * 8192;
    const size_t rq = (size_t)zi[(b >> 2)]      * 32768 + off;
    const size_t rk = (size_t)zi[8  + (b >> 2)] * 32768 + off;
    const size_t rv = (size_t)zi[16 + (b >> 2)] * 32768 + off;
    const size_t ri = (size_t)zi[24 + (b >> 2)] * 32768 + off;

    // Stage xq, xk into LDS (fp32, vectorized); stage xi column 0 into sAtt[1]
    {
        const float4* Q4 = (const float4*)(latent + rq);
        const float4* K4 = (const float4*)(latent + rk);
        for (int i = tid; i < 2048; i += 256) {
            float4 q = Q4[i], k = K4[i];
            int base = i << 2;
            int s = base >> 7, e = base & 127;
            float* dq = &sQ[s * 129 + e];
            float* dk = &sK[s * 129 + e];
            dq[0] = q.x; dq[1] = q.y; dq[2] = q.z; dq[3] = q.w;
            dk[0] = k.x; dk[1] = k.y; dk[2] = k.z; dk[3] = k.w;
        }
    }
    if (tid < 64) sAtt[1][tid] = latent[ri + (size_t)tid * 128];
    __syncthreads();

    // scores[s][t] = dot(xq[s], xk[t]) / sqrt(128); 4x4 register tile/thread
    {
        const int sb = (tid >> 4) << 2;
        const int tb = (tid & 15) << 2;
        float acc[16];
        #pragma unroll
        for (int i = 0; i < 16; ++i) acc[i] = 0.f;
        for (int e = 0; e < 128; ++e) {
            float q[4], k[4];
            #pragma unroll
            for (int i = 0; i < 4; ++i) q[i] = sQ[(sb + i) * 129 + e];
            #pragma unroll
            for (int j = 0; j < 4; ++j) k[j] = sK[(tb + j) * 129 + e];
            #pragma unroll
            for (int i = 0; i < 4; ++i)
                #pragma unroll
                for (int j = 0; j < 4; ++j) acc[i * 4 + j] = fmaf(q[i], k[j], acc[i * 4 + j]);
        }
        const float scale = 0.08838834764831843f;   // 1/sqrt(128)
        #pragma unroll
        for (int i = 0; i < 4; ++i)
            #pragma unroll
            for (int j = 0; j < 4; ++j)
                sS[(sb + i) * 65 + (tb + j)] = acc[i * 4 + j] * scale;
    }
    __syncthreads();

    // Column softmax (axis=1: over s, per column t) -> sT; att0 -> sAtt[0]
    if (tid < 64) {
        const int t = tid;
        float m = -1e30f;
        for (int s = 0; s < 64; ++s) m = fmaxf(m, sS[s * 65 + t]);
        float sum = 0.f;
        for (int s = 0; s < 64; ++s) {
            float ev = __expf(sS[s * 65 + t] - m);
            sT[s * 65 + t] = ev;
            sum += ev;
        }
        float rs = 1.0f / sum;
        for (int s = 0; s < 64; ++s) sT[s * 65 + t] *= rs;

        float m2 = -1e30f;
        for (int s = 0; s < 64; ++s) m2 = fmaxf(m2, sAtt[1][s]);
        float sum2 = 0.f;
        for (int s = 0; s < 64; ++s) sum2 += __expf(sAtt[1][s] - m2);
        sAtt[0][t] = __expf(sAtt[1][t] - m2) / sum2;
    }
    __syncthreads();

    // Register-resident columns: emit threads (tid<128) hold xv[:,e];
    // trans threads (128..191) hold xtran[:,t'].
    float xr[64];
    if (tid < 128) {
        #pragma unroll
        for (int s = 0; s < 64; ++s) xr[s] = latent[rv + (size_t)s * 128 + tid];
    } else if (tid < 192) {
        const int t2 = tid - 128;
        #pragma unroll
        for (int s = 0; s < 64; ++s) xr[s] = sT[s * 65 + t2];
    }
    __syncthreads();

    __hip_bfloat16* zrow = zs + (size_t)b * N_STEP * 128;
    int cur = 0;
    for (int t = 0; t < N_STEP; ++t) {
        if (tid < 128) {
            float a0 = 0.f, a1 = 0.f, a2 = 0.f, a3 = 0.f;
            #pragma unroll
            for (int s = 0; s < 64; s += 4) {
                float4 av = *(const float4*)&sAtt[cur][s];
                a0 = fmaf(av.x, xr[s + 0], a0);
                a1 = fmaf(av.y, xr[s + 1], a1);
                a2 = fmaf(av.z, xr[s + 2], a2);
                a3 = fmaf(av.w, xr[s + 3], a3);
            }
            zrow[t * 128 + tid] = __float2bfloat16((a0 + a1) + (a2 + a3));
        } else if (tid < 192) {
            float a0 = 0.f, a1 = 0.f, a2 = 0.f, a3 = 0.f;
            #pragma unroll
            for (int s = 0; s < 64; s += 4) {
                float4 av = *(const float4*)&sAtt[cur][s];
                a0 = fmaf(av.x, xr[s + 0], a0);
                a1 = fmaf(av.y, xr[s + 1], a1);
                a2 = fmaf(av.z, xr[s + 2], a2);
                a3 = fmaf(av.w, xr[s + 3], a3);
            }
            sAtt[cur ^ 1][tid - 128] = (a0 + a1) + (a2 + a3);
        }
        __syncthreads();
        cur ^= 1;
    }
}

// ---------------------------------------------------------------------------
// Phase B: vocab_w fp32 -> bf16 (RNE). 32000*128 = 4,096,000 elements.
// 2000 blocks x 256 threads x 8 elem/thread.
// ---------------------------------------------------------------------------
__global__ __launch_bounds__(256) void phaseB(
    const float* __restrict__ w, unsigned int* __restrict__ wb)
{
    const int t = blockIdx.x * 256 + threadIdx.x;   // 0..511999
    const float4* src = (const float4*)w;
    float4 a = src[2 * t], b = src[2 * t + 1];
    uint4 o;
    o.x = (unsigned)f2b(a.x) | ((unsigned)f2b(a.y) << 16);
    o.y = (unsigned)f2b(a.z) | ((unsigned)f2b(a.w) << 16);
    o.z = (unsigned)f2b(b.x) | ((unsigned)f2b(b.y) << 16);
    o.w = (unsigned)f2b(b.z) | ((unsigned)f2b(b.w) << 16);
    ((uint4*)wb)[t] = o;
}

// ---------------------------------------------------------------------------
// Phase C: fused logits GEMM + fixed-offset sum-exp.
// M=8192, N=32000, K=128. MFMA 16x16x32 bf16, no LDS.
// Grid: (8 vtiles, 64 mtiles), 256 threads (4 waves, N-split by wave).
// ---------------------------------------------------------------------------
__global__ __launch_bounds__(256, 2) void phaseC(
    const unsigned short* __restrict__ zs,
    const unsigned short* __restrict__ wbf,
    const float* __restrict__ vocab_b,
    float* __restrict__ partial)
{
    const int vt   = blockIdx.x;      // 0..7
    const int mt   = blockIdx.y;      // 0..63
    const int tid  = threadIdx.x;
    const int wave = tid >> 6;
    const int lane = tid & 63;
    const int q    = lane >> 4;       // k-quad
    const int l    = lane & 15;       // m/n within fragment

    // A frags: A[m=lane&15][k=q*8+j]
    const uint4* A16 = (const uint4*)zs;
    const int arow = mt * 128 + l;
    bf16_8 a[8][4];
    #pragma unroll
    for (int mf = 0; mf < 8; ++mf)
        #pragma unroll
        for (int ks = 0; ks < 4; ++ks)
            a[mf][ks] = __builtin_bit_cast(bf16_8, A16[(size_t)(arow + mf * 16) * 16 + ks * 4 + q]);

    float sacc[8][4];
    #pragma unroll
    for (int mf = 0; mf < 8; ++mf)
        #pragma unroll
        for (int r = 0; r < 4; ++r) sacc[mf][r] = 0.f;

    const uint4* W16 = (const uint4*)wbf;
    const int inner0 = wave * 16 + l;            // 0..63 within chunk
    const int colbase = vt * 4000 + inner0;

    for (int c = 0; c < 63; ++c) {               // 63*64 = 4032 >= 4000
        const int inner = c * 64 + inner0;
        const bool valid = inner < 4000;
        const int col = colbase + c * 64;
        const int rowc = valid ? col : 0;

        bf16_8 bfrag[4];
        #pragma unroll
        for (int ks = 0; ks < 4; ++ks)
            bfrag[ks] = __builtin_bit_cast(bf16_8, W16[(size_t)rowc * 16 + ks * 4 + q]);
        const float ebb = valid ? (vocab_b[rowc] - C0) : -1e30f;

        f32x4 acc[8];
        #pragma unroll
        for (int mf = 0; mf < 8; ++mf) acc[mf] = (f32x4){0.f, 0.f, 0.f, 0.f};
        #pragma unroll
        for (int ks = 0; ks < 4; ++ks)
            #pragma unroll
            for (int mf = 0; mf < 8; ++mf)
                acc[mf] = __builtin_amdgcn_mfma_f32_16x16x32_bf16(a[mf][ks], bfrag[ks], acc[mf], 0, 0, 0);

        #pragma unroll
        for (int mf = 0; mf < 8; ++mf)
            #pragma unroll
            for (int r = 0; r < 4; ++r)
                sacc[mf][r] += __expf(acc[mf][r] + ebb);   // masked: exp(-1e30)=0
    }

    // Reduce over the 16 columns (low 4 lane bits)
    #pragma unroll
    for (int mf = 0; mf < 8; ++mf)
        #pragma unroll
        for (int r = 0; r < 4; ++r) {
            float v = sacc[mf][r];
            v += __shfl_xor(v, 1);
            v += __shfl_xor(v, 2);
            v += __shfl_xor(v, 4);
            v += __shfl_xor(v, 8);
            sacc[mf][r] = v;
        }

    if (l == 0) {
        float* dst = partial + (size_t)(vt * 4 + wave) * 8192 + mt * 128;
        #pragma unroll
        for (int mf = 0; mf < 8; ++mf)
            #pragma unroll
            for (int r = 0; r < 4; ++r)
                dst[mf * 16 + q * 4 + r] = sacc[mf][r];
    }
}

// ---------------------------------------------------------------------------
// Phase D: combine 32 partials, recompute target logit (fp32 W), emit fp32 yp.
// ---------------------------------------------------------------------------
__global__ __launch_bounds__(256) void phaseD(
    const unsigned short* __restrict__ zs,
    const float* __restrict__ vocab_w,
    const float* __restrict__ vocab_b,
    const int* __restrict__ y,
    const float* __restrict__ partial,
    float* __restrict__ out)
{
    const int r = blockIdx.x * 256 + threadIdx.x;   // 0..8191 = b*256+t
    const int v = y[r];

    const uint4*  zp = (const uint4*)(zs + (size_t)r * 128);       // 16 x 8 bf16
    const float4* wp = (const float4*)(vocab_w + (size_t)v * 128); // 32 x 4 f32
    float dot = 0.f;
    #pragma unroll
    for (int i = 0; i < 16; ++i) {
        uint4 z = zp[i];
        float4 w0 = wp[2 * i], w1 = wp[2 * i + 1];
        dot += blo(z.x) * w0.x + bhi(z.x) * w0.y;
        dot += blo(z.y) * w0.z + bhi(z.y) * w0.w;
        dot += blo(z.z) * w1.x + bhi(z.z) * w1.y;
        dot += blo(z.w) * w1.z + bhi(z.w) * w1.w;
    }

    float st = 0.f;
    #pragma unroll
    for (int p = 0; p < 32; ++p) st += partial[(size_t)p * 8192 + r];

    const float lse = C0 + __logf(st);
    out[r] = dot + vocab_b[v] - lse;
}

extern "C" void kernel_launch(void* const* d_in, const int* in_sizes, int n_in,
                              void* d_out, int out_size, void* d_ws, size_t ws_size,
                              hipStream_t stream) {
    const float* latent = (const float*)d_in[0];
    const float* vw     = (const float*)d_in[1];
    const float* vb     = (const float*)d_in[2];
    const int*   zi     = (const int*)d_in[3];
    const int*   y      = (const int*)d_in[4];

    unsigned short* zs      = (unsigned short*)d_ws;                            // 2 MB
    float*          partial = (float*)((char*)d_ws + (2u << 20));               // 1 MB
    unsigned short* wbf     = (unsigned short*)((char*)d_ws + (3u << 20));      // 8 MB
    float*          out     = (float*)d_out;

    phaseB<<<dim3(2000), dim3(256), 0, stream>>>(vw, (unsigned int*)wbf);
    phaseA<<<dim3(BATCH), dim3(256), 0, stream>>>(latent, zi, (__hip_bfloat16*)zs);
    phaseC<<<dim3(8, 64), dim3(256), 0, stream>>>(zs, wbf, vb, partial);
    phaseD<<<dim3(32), dim3(256), 0, stream>>>(zs, vw, vb, y, partial, out);
}